// Round 10
// baseline (477.208 us; speedup 1.0000x reference)
//
#include <hip/hip_runtime.h>
#include <hip/hip_bf16.h>

// Inputs q,k,v are FLOAT32; output FLOAT32 (confirmed R2/R7).

#define H_  16
#define L_  8192
#define D_  64
#define MB_ 128   // query blocks (L/64)
#define NB_ 128   // kv blocks
#define TK_ 16    // top-k kv blocks per query block
#define ST_ 72    // LDS row stride for phase-1 v transpose tile

typedef __bf16 bf16x8 __attribute__((ext_vector_type(8)));
typedef __bf16 bf16x4 __attribute__((ext_vector_type(4)));
typedef short  s16x4  __attribute__((ext_vector_type(4)));
typedef float  f32x4  __attribute__((ext_vector_type(4)));
typedef unsigned short u16x8 __attribute__((ext_vector_type(8)));

union BFU { __hip_bfloat16 h; unsigned short u; };

static __device__ inline unsigned short f2bfu(float f) {
  BFU c; c.h = __float2bfloat16(f); return c.u;
}

static __device__ inline f32x4 mfma16(bf16x4 a, bf16x4 b, f32x4 c) {
#if __has_builtin(__builtin_amdgcn_mfma_f32_16x16x16bf16_1k)
  return __builtin_amdgcn_mfma_f32_16x16x16bf16_1k(
      __builtin_bit_cast(s16x4, a), __builtin_bit_cast(s16x4, b), c, 0, 0, 0);
#elif __has_builtin(__builtin_amdgcn_mfma_f32_16x16x16_bf16)
  return __builtin_amdgcn_mfma_f32_16x16x16_bf16(a, b, c, 0, 0, 0);
#else
  f32x4 d = c;
  asm("v_mfma_f32_16x16x16_bf16 %0, %1, %2, %0" : "+v"(d) : "v"(a), "v"(b));
  return d;
#endif
}

static __device__ inline bf16x4 lo4(bf16x8 v) {
  return __builtin_shufflevector(v, v, 0, 1, 2, 3);
}
static __device__ inline bf16x4 hi4(bf16x8 v) {
  return __builtin_shufflevector(v, v, 4, 5, 6, 7);
}

// module-scope scratch (round-3 lesson: never trust d_ws for the lut)
__device__ unsigned short g_qb[(size_t)H_ * L_ * D_];  // q*(sm_scale*log2e), row-major bf16
// K in MFMA-FRAGMENT order: [h][n][wkv][half][lane=quad*16+l16][8]
//   frag elem: K[16wkv+l16][32*half + quad*8 + i]
__device__ unsigned short g_kf[(size_t)H_ * NB_ * 4096];
// V^T in MFMA-FRAGMENT order: [h][n][wkv][lane][n4][4]
//   frag elem: V[16wkv + quad*4 + r][16*n4 + l16]  (= V^T[d][kv])
__device__ unsigned short g_vf[(size_t)H_ * NB_ * 4096];
__device__ float g_qpool[H_ * NB_ * 64];
__device__ float g_kpool[H_ * NB_ * 64];

static __device__ inline void cvt8_2(const float4& f0, const float4& f1,
                                     unsigned short* dst) {
  u16x8 s;
  s[0] = f2bfu(f0.x); s[1] = f2bfu(f0.y); s[2] = f2bfu(f0.z); s[3] = f2bfu(f0.w);
  s[4] = f2bfu(f1.x); s[5] = f2bfu(f1.y); s[6] = f2bfu(f1.z); s[7] = f2bfu(f1.w);
  *(u16x8*)dst = s;
}

static __device__ inline void cvt8_2s(const float4& f0, const float4& f1,
                                      unsigned short* dst, float sc) {
  u16x8 s;
  s[0] = f2bfu(f0.x * sc); s[1] = f2bfu(f0.y * sc);
  s[2] = f2bfu(f0.z * sc); s[3] = f2bfu(f0.w * sc);
  s[4] = f2bfu(f1.x * sc); s[5] = f2bfu(f1.y * sc);
  s[6] = f2bfu(f1.z * sc); s[7] = f2bfu(f1.w * sc);
  *(u16x8*)dst = s;
}

// -------- phase 1: f32->bf16 convert + FRAGMENT-ORDER K/V + pooling ------
__global__ __launch_bounds__(256)
void fusedpool_kernel(const float* __restrict__ q,
                      const float* __restrict__ k,
                      const float* __restrict__ v) {
  __shared__ float qt[64 * 64];
  __shared__ float kt[64 * 64];
  __shared__ __align__(16) unsigned short vt_s[64 * ST_];  // bf16 v tile [kk][d]
  __shared__ float pq[4][64], pk[4][64];

  const int b = blockIdx.x;           // h*NB_ + n
  const int t = threadIdx.x;
  const int r = t >> 2, c = (t & 3) * 16;
  const size_t base = (size_t)b * 4096 + r * 64 + c;
  const float cs = 0.18033688011112042f;  // (1/sqrt(64)) * log2(e), baked into Q

  float4 qf0 = *(const float4*)(q + base),      qf1 = *(const float4*)(q + base + 4);
  float4 qf2 = *(const float4*)(q + base + 8),  qf3 = *(const float4*)(q + base + 12);
  float4 kf0 = *(const float4*)(k + base),      kf1 = *(const float4*)(k + base + 4);
  float4 kf2 = *(const float4*)(k + base + 8),  kf3 = *(const float4*)(k + base + 12);
  float4 vf0 = *(const float4*)(v + base),      vf1 = *(const float4*)(v + base + 4);
  float4 vf2 = *(const float4*)(v + base + 8),  vf3 = *(const float4*)(v + base + 12);

  // scaled Q straight to global bf16 (row-major)
  cvt8_2s(qf0, qf1, g_qb + base, cs);  cvt8_2s(qf2, qf3, g_qb + base + 8, cs);

  // K straight from registers into FRAGMENT order:
  // this thread holds row r, cols [c,c+16) = half hf=c>>5, quads quadA,quadA+1
  {
    const int w_k = r >> 4, l16k = r & 15;
    const int hf = c >> 5, quadA = (c & 31) >> 3;
    unsigned short* kfp = g_kf + ((size_t)b * 4 + w_k) * 1024 + hf * 512 + l16k * 8;
    cvt8_2(kf0, kf1, kfp + quadA * 128);
    cvt8_2(kf2, kf3, kfp + (quadA + 1) * 128);
  }

  // V bf16 into LDS for transpose (row=kk, col=d; 144B stride keeps 16B align)
  cvt8_2(vf0, vf1, vt_s + r * ST_ + c);
  cvt8_2(vf2, vf3, vt_s + r * ST_ + c + 8);

  // stash f32 q,k tiles for exact pooling (unscaled: lut must match reference)
  *(float4*)(qt + r * 64 + c)      = qf0; *(float4*)(qt + r * 64 + c + 4)  = qf1;
  *(float4*)(qt + r * 64 + c + 8)  = qf2; *(float4*)(qt + r * 64 + c + 12) = qf3;
  *(float4*)(kt + r * 64 + c)      = kf0; *(float4*)(kt + r * 64 + c + 4)  = kf1;
  *(float4*)(kt + r * 64 + c + 8)  = kf2; *(float4*)(kt + r * 64 + c + 12) = kf3;
  __syncthreads();

  const int col = t & 63, g = t >> 6;
  float sq = 0.f, sk = 0.f;
  for (int rr = g * 16; rr < g * 16 + 16; ++rr) {
    sq += qt[rr * 64 + col];
    sk += kt[rr * 64 + col];
  }
  pq[g][col] = sq; pk[g][col] = sk;

  // V into FRAGMENT order: thread t = (wave-slice wv, lane lv)
  // frag[lv][n4*4+rr] = V[16wv + quadv*4 + rr][16n4 + l16v]
  {
    const int wv = t >> 6, lv = t & 63;
    const int l16v = lv & 15, quadv = lv >> 4;
    u16x8 f0, f1;
    #pragma unroll
    for (int n4 = 0; n4 < 2; ++n4)
      #pragma unroll
      for (int rr = 0; rr < 4; ++rr)
        f0[n4 * 4 + rr] = vt_s[(16 * wv + quadv * 4 + rr) * ST_ + 16 * n4 + l16v];
    #pragma unroll
    for (int n4 = 2; n4 < 4; ++n4)
      #pragma unroll
      for (int rr = 0; rr < 4; ++rr)
        f1[(n4 - 2) * 4 + rr] = vt_s[(16 * wv + quadv * 4 + rr) * ST_ + 16 * n4 + l16v];
    unsigned short* vfp = g_vf + ((size_t)b * 4 + wv) * 1024 + lv * 16;
    *(u16x8*)(vfp)     = f0;
    *(u16x8*)(vfp + 8) = f1;
  }

  __syncthreads();
  if (t < 64) {
    g_qpool[b * 64 + t] = (pq[0][t] + pq[1][t] + pq[2][t] + pq[3][t]) * (1.f / 64.f);
    g_kpool[b * 64 + t] = (pk[0][t] + pk[1][t] + pk[2][t] + pk[3][t]) * (1.f / 64.f);
  }
}

// NOTE: center_kernel deleted (rank-preserving per-row shift; R3-verified).
// NOTE: topk merged into attn (R8/R9: −20us launch+lut overhead). R9 lesson:
// the merged topk must NOT serialize — pred is computed by 128 threads in
// parallel (exact FP order preserved), and the 16 serial argmax rounds run
// REDUNDANTLY per-wave, interleaved with the main loop so they hide under
// the MFMA compute phase.

// -------- phase 2: parallel-topk prologue + sparse flash attention -------
// 4 waves; wave w owns kv rows [16w,16w+16) for ALL 64 q (Q in registers).
// K and V pre-permuted into fragment order by phase 1: every main-loop load
// is a coalesced burst. ZERO LDS ops and ZERO barriers in the main loop
// (selection shuffles are register/DPP ops). 24 MFMA/iter per wave hides
// the next-buffer load latency (R8 lesson).
__global__ __launch_bounds__(256, 3)
void attn_kernel(float* __restrict__ out) {
  __shared__ float LDSo[4][16][65];   // per-wave O^T slice, per d-chunk
  __shared__ float LDSr[4][64];       // per-wave partial rowsums
  __shared__ float sc_s[NB_];         // block scores (topk prologue)

  const int flat = blockIdx.x;
  // bijective: xcd = flat&7 -> heads 2*xcd, 2*xcd+1 live on one XCD,
  // and each XCD runs one head's 128 blocks before the other.
  const int h = (flat & 7) * 2 + ((flat >> 10) & 1);
  const int m = (flat >> 3) & 127;
  const int t = threadIdx.x;
  const int w = t >> 6;                // wave id: kv rows 16w..16w+15
  const int lane = t & 63;
  const int l16 = lane & 15, quad = lane >> 4;

  // Q in registers (all waves; overlaps the pred compute below)
  const unsigned short* qg = g_qb + ((size_t)h * L_ + (size_t)m * 64) * D_;
  bf16x8 qb0[4], qb1[4];
  #pragma unroll
  for (int g = 0; g < 4; ++g) {
    const unsigned short* qp = qg + (16 * g + l16) * 64 + quad * 8;
    qb0[g] = *(const bf16x8*)(qp);
    qb1[g] = *(const bf16x8*)(qp + 32);
  }

  // ---- parallel pred: thread t<128 computes score[n=t], EXACT topk FP order
  if (t < NB_) {
    const int b = h * MB_ + m;
    const float4* qrow4 = (const float4*)(g_qpool + b * 64);
    const float4* kp = (const float4*)(g_kpool + (h * NB_ + t) * 64);
    float s0 = 0.f;
    for (int i = 0; i < 16; ++i) {
      float4 qv = qrow4[i];
      float4 a = kp[i];
      s0 += qv.x * a.x + qv.y * a.y + qv.z * a.z + qv.w * a.w;
    }
    sc_s[t] = s0;
  }
  __syncthreads();                     // scores visible; ONLY barrier pre-loop

  // each wave holds its own redundant copy of the selection state
  float sv0 = sc_s[lane], sv1 = sc_s[lane + 64];

  f32x4 o[4][4];                       // o[n4][g] = O^T[16n4+...][16g+l16]
  #pragma unroll
  for (int n4 = 0; n4 < 4; ++n4)
    #pragma unroll
    for (int g = 0; g < 4; ++g) o[n4][g] = (f32x4){0.f, 0.f, 0.f, 0.f};
  float lsum[4] = {0.f, 0.f, 0.f, 0.f};

  const unsigned short* kfh = g_kf + (size_t)h * NB_ * 4096;
  const unsigned short* vfh = g_vf + (size_t)h * NB_ * 4096;

  // one argmax round: exact topk compare/suppress logic; bi is wave-uniform
  // after the butterfly (ties -> lower index, matches jax.lax.top_k set).
  auto argmax_round = [&]() -> int {
    float bv; int bi;
    if (sv0 >= sv1) { bv = sv0; bi = lane; } else { bv = sv1; bi = lane + 64; }
    #pragma unroll
    for (int mask = 1; mask < 64; mask <<= 1) {
      float ov = __shfl_xor(bv, mask, 64);
      int   oi = __shfl_xor(bi, mask, 64);
      if (ov > bv || (ov == bv && oi < bi)) { bv = ov; bi = oi; }
    }
    if (bi == lane) sv0 = -3.0e38f;
    else if (bi == lane + 64) sv1 = -3.0e38f;
    return __builtin_amdgcn_readfirstlane(bi);
  };

  // fragment double-buffers (compile-time indexed after full unroll)
  bf16x8 ka0[2], ka1[2], vv01[2], vv23[2];

  // prologue: select block 0, load its fragments (coalesced bursts)
  {
    const int kb0 = argmax_round();
    const unsigned short* kbp = kfh + ((size_t)kb0 * 4 + w) * 1024;
    ka0[0] = *(const bf16x8*)(kbp + lane * 8);
    ka1[0] = *(const bf16x8*)(kbp + 512 + lane * 8);
    const unsigned short* vbp = vfh + ((size_t)kb0 * 4 + w) * 1024 + lane * 16;
    vv01[0] = *(const bf16x8*)(vbp);
    vv23[0] = *(const bf16x8*)(vbp + 8);
  }

  #pragma unroll
  for (int j = 0; j < TK_; ++j) {
    const int cb = j & 1, nb = cb ^ 1;
    // select next block + issue its loads; the argmax chain and the load
    // latency both hide under this iteration's 24-MFMA compute phase
    if (j + 1 < TK_) {
      const int kbn = argmax_round();
      const unsigned short* kbp = kfh + ((size_t)kbn * 4 + w) * 1024;
      ka0[nb] = *(const bf16x8*)(kbp + lane * 8);
      ka1[nb] = *(const bf16x8*)(kbp + 512 + lane * 8);
      const unsigned short* vbp = vfh + ((size_t)kbn * 4 + w) * 1024 + lane * 16;
      vv01[nb] = *(const bf16x8*)(vbp);
      vv23[nb] = *(const bf16x8*)(vbp + 8);
    }

    // ---- S = K Q^T : acc[g][r] = S[q=16g+l16][kv=16w+4quad+r] ------------
    f32x4 acc[4];
    __builtin_amdgcn_s_setprio(1);
    #pragma unroll
    for (int g = 0; g < 4; ++g) {
      f32x4 z = (f32x4){0.f, 0.f, 0.f, 0.f};
      z = __builtin_amdgcn_mfma_f32_16x16x32_bf16(ka0[cb], qb0[g], z, 0, 0, 0);
      z = __builtin_amdgcn_mfma_f32_16x16x32_bf16(ka1[cb], qb1[g], z, 0, 0, 0);
      acc[g] = z;
    }
    __builtin_amdgcn_s_setprio(0);

    // ---- no-max softmax (pre-scaled log2 units) + in-lane pack -----------
    bf16x4 pb[4];
    #pragma unroll
    for (int g = 0; g < 4; ++g) {
      const float p0 = exp2f(acc[g][0]), p1 = exp2f(acc[g][1]);
      const float p2 = exp2f(acc[g][2]), p3 = exp2f(acc[g][3]);
      lsum[g] += (p0 + p1) + (p2 + p3);
      unsigned int d0, d1;
      asm("v_cvt_pk_bf16_f32 %0, %1, %2" : "=v"(d0) : "v"(p0), "v"(p1));
      asm("v_cvt_pk_bf16_f32 %0, %1, %2" : "=v"(d1) : "v"(p2), "v"(p3));
      uint2 dd; dd.x = d0; dd.y = d1;
      pb[g] = __builtin_bit_cast(bf16x4, dd);
    }

    // ---- O^T += V^T P^T : 16x16x16, A and B straight from registers ------
    const bf16x4 va_[4] = { lo4(vv01[cb]), hi4(vv01[cb]),
                            lo4(vv23[cb]), hi4(vv23[cb]) };
    __builtin_amdgcn_s_setprio(1);
    #pragma unroll
    for (int n4 = 0; n4 < 4; ++n4)
      #pragma unroll
      for (int g = 0; g < 4; ++g)
        o[n4][g] = mfma16(va_[n4], pb[g], o[n4][g]);
    __builtin_amdgcn_s_setprio(0);
  }

  // ---- epilogue: cross-wave reduce (one-time) ----------------------------
  #pragma unroll
  for (int g = 0; g < 4; ++g) {
    float rs = lsum[g];
    rs += __shfl_xor(rs, 16, 64);
    rs += __shfl_xor(rs, 32, 64);
    lsum[g] = rs;                      // uniform across quads
  }
  if (quad == 0) {
    #pragma unroll
    for (int g = 0; g < 4; ++g) LDSr[w][16 * g + l16] = lsum[g];
  }
  __syncthreads();

  const int dr = t & 15, q0 = (t >> 4) * 4;
  float rinv[4];
  #pragma unroll
  for (int qq = 0; qq < 4; ++qq)
    rinv[qq] = 1.0f / (LDSr[0][q0 + qq] + LDSr[1][q0 + qq] +
                       LDSr[2][q0 + qq] + LDSr[3][q0 + qq]);

  const size_t obase = ((size_t)h * L_ + (size_t)m * 64) * D_;
  #pragma unroll
  for (int n4 = 0; n4 < 4; ++n4) {
    // publish this wave's O^T d-chunk
    #pragma unroll
    for (int g = 0; g < 4; ++g)
      #pragma unroll
      for (int r = 0; r < 4; ++r)
        LDSo[w][quad * 4 + r][16 * g + l16] = o[n4][g][r];
    __syncthreads();
    // sum 4 waves, normalize, store (coalesced 64B runs along d)
    #pragma unroll
    for (int qq = 0; qq < 4; ++qq) {
      const int qv = q0 + qq;
      const float s = LDSo[0][dr][qv] + LDSo[1][dr][qv] +
                      LDSo[2][dr][qv] + LDSo[3][dr][qv];
      out[obase + (size_t)qv * 64 + n4 * 16 + dr] = s * rinv[qq];
    }
    __syncthreads();
  }
}

extern "C" void kernel_launch(void* const* d_in, const int* in_sizes, int n_in,
                              void* d_out, int out_size, void* d_ws, size_t ws_size,
                              hipStream_t stream) {
  const float* q = (const float*)d_in[0];
  const float* k = (const float*)d_in[1];
  const float* v = (const float*)d_in[2];
  float* out = (float*)d_out;

  fusedpool_kernel<<<H_ * NB_, 256, 0, stream>>>(q, k, v);
  attn_kernel<<<H_ * MB_, 256, 0, stream>>>(out);
}

// Round 11
// 222.048 us; speedup vs baseline: 2.1491x; 2.1491x over previous
//
#include <hip/hip_runtime.h>
#include <hip/hip_bf16.h>

// Inputs q,k,v are FLOAT32; output FLOAT32 (confirmed R2/R7).

#define H_  16
#define L_  8192
#define D_  64
#define MB_ 128   // query blocks (L/64)
#define NB_ 128   // kv blocks
#define TK_ 16    // top-k kv blocks per query block
#define ST_ 72    // LDS row stride for phase-1 v transpose tile

typedef __bf16 bf16x8 __attribute__((ext_vector_type(8)));
typedef __bf16 bf16x4 __attribute__((ext_vector_type(4)));
typedef short  s16x4  __attribute__((ext_vector_type(4)));
typedef float  f32x4  __attribute__((ext_vector_type(4)));
typedef unsigned short u16x8 __attribute__((ext_vector_type(8)));

union BFU { __hip_bfloat16 h; unsigned short u; };

static __device__ inline unsigned short f2bfu(float f) {
  BFU c; c.h = __float2bfloat16(f); return c.u;
}

static __device__ inline f32x4 mfma16(bf16x4 a, bf16x4 b, f32x4 c) {
#if __has_builtin(__builtin_amdgcn_mfma_f32_16x16x16bf16_1k)
  return __builtin_amdgcn_mfma_f32_16x16x16bf16_1k(
      __builtin_bit_cast(s16x4, a), __builtin_bit_cast(s16x4, b), c, 0, 0, 0);
#elif __has_builtin(__builtin_amdgcn_mfma_f32_16x16x16_bf16)
  return __builtin_amdgcn_mfma_f32_16x16x16_bf16(a, b, c, 0, 0, 0);
#else
  f32x4 d = c;
  asm("v_mfma_f32_16x16x16_bf16 %0, %1, %2, %0" : "+v"(d) : "v"(a), "v"(b));
  return d;
#endif
}

static __device__ inline bf16x4 lo4(bf16x8 v) {
  return __builtin_shufflevector(v, v, 0, 1, 2, 3);
}
static __device__ inline bf16x4 hi4(bf16x8 v) {
  return __builtin_shufflevector(v, v, 4, 5, 6, 7);
}

// module-scope scratch (round-3 lesson: never trust d_ws for the lut)
__device__ unsigned short g_qb[(size_t)H_ * L_ * D_];  // q*(sm_scale*log2e), row-major bf16
// K in MFMA-FRAGMENT order: [h][n][wkv][half][lane=quad*16+l16][8]
//   frag elem: K[16wkv+l16][32*half + quad*8 + i]
__device__ unsigned short g_kf[(size_t)H_ * NB_ * 4096];
// V^T in MFMA-FRAGMENT order: [h][n][wkv][lane][n4][4]
//   frag elem: V[16wkv + quad*4 + r][16*n4 + l16]  (= V^T[d][kv])
__device__ unsigned short g_vf[(size_t)H_ * NB_ * 4096];
__device__ float g_qpool[H_ * NB_ * 64];
__device__ float g_kpool[H_ * NB_ * 64];

static __device__ inline void cvt8_2(const float4& f0, const float4& f1,
                                     unsigned short* dst) {
  u16x8 s;
  s[0] = f2bfu(f0.x); s[1] = f2bfu(f0.y); s[2] = f2bfu(f0.z); s[3] = f2bfu(f0.w);
  s[4] = f2bfu(f1.x); s[5] = f2bfu(f1.y); s[6] = f2bfu(f1.z); s[7] = f2bfu(f1.w);
  *(u16x8*)dst = s;
}

static __device__ inline void cvt8_2s(const float4& f0, const float4& f1,
                                      unsigned short* dst, float sc) {
  u16x8 s;
  s[0] = f2bfu(f0.x * sc); s[1] = f2bfu(f0.y * sc);
  s[2] = f2bfu(f0.z * sc); s[3] = f2bfu(f0.w * sc);
  s[4] = f2bfu(f1.x * sc); s[5] = f2bfu(f1.y * sc);
  s[6] = f2bfu(f1.z * sc); s[7] = f2bfu(f1.w * sc);
  *(u16x8*)dst = s;
}

// -------- phase 1: f32->bf16 convert + FRAGMENT-ORDER K/V + pooling ------
__global__ __launch_bounds__(256)
void fusedpool_kernel(const float* __restrict__ q,
                      const float* __restrict__ k,
                      const float* __restrict__ v) {
  __shared__ float qt[64 * 64];
  __shared__ float kt[64 * 64];
  __shared__ __align__(16) unsigned short vt_s[64 * ST_];  // bf16 v tile [kk][d]
  __shared__ float pq[4][64], pk[4][64];

  const int b = blockIdx.x;           // h*NB_ + n
  const int t = threadIdx.x;
  const int r = t >> 2, c = (t & 3) * 16;
  const size_t base = (size_t)b * 4096 + r * 64 + c;
  const float cs = 0.18033688011112042f;  // (1/sqrt(64)) * log2(e), baked into Q

  float4 qf0 = *(const float4*)(q + base),      qf1 = *(const float4*)(q + base + 4);
  float4 qf2 = *(const float4*)(q + base + 8),  qf3 = *(const float4*)(q + base + 12);
  float4 kf0 = *(const float4*)(k + base),      kf1 = *(const float4*)(k + base + 4);
  float4 kf2 = *(const float4*)(k + base + 8),  kf3 = *(const float4*)(k + base + 12);
  float4 vf0 = *(const float4*)(v + base),      vf1 = *(const float4*)(v + base + 4);
  float4 vf2 = *(const float4*)(v + base + 8),  vf3 = *(const float4*)(v + base + 12);

  // scaled Q straight to global bf16 (row-major)
  cvt8_2s(qf0, qf1, g_qb + base, cs);  cvt8_2s(qf2, qf3, g_qb + base + 8, cs);

  // K straight from registers into FRAGMENT order:
  // this thread holds row r, cols [c,c+16) = half hf=c>>5, quads quadA,quadA+1
  {
    const int w_k = r >> 4, l16k = r & 15;
    const int hf = c >> 5, quadA = (c & 31) >> 3;
    unsigned short* kfp = g_kf + ((size_t)b * 4 + w_k) * 1024 + hf * 512 + l16k * 8;
    cvt8_2(kf0, kf1, kfp + quadA * 128);
    cvt8_2(kf2, kf3, kfp + (quadA + 1) * 128);
  }

  // V bf16 into LDS for transpose (row=kk, col=d; 144B stride keeps 16B align)
  cvt8_2(vf0, vf1, vt_s + r * ST_ + c);
  cvt8_2(vf2, vf3, vt_s + r * ST_ + c + 8);

  // stash f32 q,k tiles for exact pooling (unscaled: lut must match reference)
  *(float4*)(qt + r * 64 + c)      = qf0; *(float4*)(qt + r * 64 + c + 4)  = qf1;
  *(float4*)(qt + r * 64 + c + 8)  = qf2; *(float4*)(qt + r * 64 + c + 12) = qf3;
  *(float4*)(kt + r * 64 + c)      = kf0; *(float4*)(kt + r * 64 + c + 4)  = kf1;
  *(float4*)(kt + r * 64 + c + 8)  = kf2; *(float4*)(kt + r * 64 + c + 12) = kf3;
  __syncthreads();

  const int col = t & 63, g = t >> 6;
  float sq = 0.f, sk = 0.f;
  for (int rr = g * 16; rr < g * 16 + 16; ++rr) {
    sq += qt[rr * 64 + col];
    sk += kt[rr * 64 + col];
  }
  pq[g][col] = sq; pk[g][col] = sk;

  // V into FRAGMENT order: thread t = (wave-slice wv, lane lv)
  // frag[lv][n4*4+rr] = V[16wv + quadv*4 + rr][16n4 + l16v]
  {
    const int wv = t >> 6, lv = t & 63;
    const int l16v = lv & 15, quadv = lv >> 4;
    u16x8 f0, f1;
    #pragma unroll
    for (int n4 = 0; n4 < 2; ++n4)
      #pragma unroll
      for (int rr = 0; rr < 4; ++rr)
        f0[n4 * 4 + rr] = vt_s[(16 * wv + quadv * 4 + rr) * ST_ + 16 * n4 + l16v];
    #pragma unroll
    for (int n4 = 2; n4 < 4; ++n4)
      #pragma unroll
      for (int rr = 0; rr < 4; ++rr)
        f1[(n4 - 2) * 4 + rr] = vt_s[(16 * wv + quadv * 4 + rr) * ST_ + 16 * n4 + l16v];
    unsigned short* vfp = g_vf + ((size_t)b * 4 + wv) * 1024 + lv * 16;
    *(u16x8*)(vfp)     = f0;
    *(u16x8*)(vfp + 8) = f1;
  }

  __syncthreads();
  if (t < 64) {
    g_qpool[b * 64 + t] = (pq[0][t] + pq[1][t] + pq[2][t] + pq[3][t]) * (1.f / 64.f);
    g_kpool[b * 64 + t] = (pk[0][t] + pk[1][t] + pk[2][t] + pk[3][t]) * (1.f / 64.f);
  }
}

// NOTE: center_kernel deleted (rank-preserving per-row shift; R3-verified).
// NOTE: topk merged into attn (−20us launch+lut, R8/R9-verified). R9 lesson:
// don't serialize on one wave. R10 lesson (rule #20): don't put the argmax
// INSIDE the main loop — the bloated body stopped full unroll, runtime cb
// indexed the ext-vector double-buffers, everything spilled to scratch
// (FETCH 27->469 MB). So: parallel pred, then ALL 16 argmax rounds UPFRONT
// (per-wave redundant, ~1-2us, no idle waves), then the R7-verified loop
// body untouched with static lut_r[] indices.

// -------- phase 2: parallel-topk prologue + sparse flash attention -------
// 4 waves; wave w owns kv rows [16w,16w+16) for ALL 64 q (Q in registers).
// K and V pre-permuted into fragment order by phase 1: every main-loop load
// is a coalesced burst. ZERO LDS ops and ZERO barriers in the main loop.
// 24 MFMA/iter per wave hides the next-buffer load latency (R8 lesson).
__global__ __launch_bounds__(256, 3)
void attn_kernel(float* __restrict__ out) {
  __shared__ float LDSo[4][16][65];   // per-wave O^T slice, per d-chunk
  __shared__ float LDSr[4][64];       // per-wave partial rowsums
  __shared__ float sc_s[NB_];         // block scores (topk prologue)

  const int flat = blockIdx.x;
  // bijective: xcd = flat&7 -> heads 2*xcd, 2*xcd+1 live on one XCD,
  // and each XCD runs one head's 128 blocks before the other.
  const int h = (flat & 7) * 2 + ((flat >> 10) & 1);
  const int m = (flat >> 3) & 127;
  const int t = threadIdx.x;
  const int w = t >> 6;                // wave id: kv rows 16w..16w+15
  const int lane = t & 63;
  const int l16 = lane & 15, quad = lane >> 4;

  // Q in registers (all waves; overlaps the pred compute below)
  const unsigned short* qg = g_qb + ((size_t)h * L_ + (size_t)m * 64) * D_;
  bf16x8 qb0[4], qb1[4];
  #pragma unroll
  for (int g = 0; g < 4; ++g) {
    const unsigned short* qp = qg + (16 * g + l16) * 64 + quad * 8;
    qb0[g] = *(const bf16x8*)(qp);
    qb1[g] = *(const bf16x8*)(qp + 32);
  }

  // ---- parallel pred: thread t<128 computes score[n=t], EXACT topk FP order
  if (t < NB_) {
    const int b = h * MB_ + m;
    const float4* qrow4 = (const float4*)(g_qpool + b * 64);
    const float4* kp = (const float4*)(g_kpool + (h * NB_ + t) * 64);
    float s0 = 0.f;
    for (int i = 0; i < 16; ++i) {
      float4 qv = qrow4[i];
      float4 a = kp[i];
      s0 += qv.x * a.x + qv.y * a.y + qv.z * a.z + qv.w * a.w;
    }
    sc_s[t] = s0;
  }
  __syncthreads();                     // scores visible; ONLY barrier pre-loop

  // ---- per-wave redundant selection: ALL 16 rounds upfront ---------------
  // bi is wave-uniform after the butterfly; lut_r[] -> SGPRs (static index
  // in the fully-unrolled main loop). Ties -> lower index = jax.lax.top_k.
  float sv0 = sc_s[lane], sv1 = sc_s[lane + 64];
  int lut_r[TK_];
  #pragma unroll
  for (int tt = 0; tt < TK_; ++tt) {
    float bv; int bi;
    if (sv0 >= sv1) { bv = sv0; bi = lane; } else { bv = sv1; bi = lane + 64; }
    #pragma unroll
    for (int mask = 1; mask < 64; mask <<= 1) {
      float ov = __shfl_xor(bv, mask, 64);
      int   oi = __shfl_xor(bi, mask, 64);
      if (ov > bv || (ov == bv && oi < bi)) { bv = ov; bi = oi; }
    }
    if (bi == lane) sv0 = -3.0e38f;
    else if (bi == lane + 64) sv1 = -3.0e38f;
    lut_r[tt] = __builtin_amdgcn_readfirstlane(bi);
  }

  f32x4 o[4][4];                       // o[n4][g] = O^T[16n4+...][16g+l16]
  #pragma unroll
  for (int n4 = 0; n4 < 4; ++n4)
    #pragma unroll
    for (int g = 0; g < 4; ++g) o[n4][g] = (f32x4){0.f, 0.f, 0.f, 0.f};
  float lsum[4] = {0.f, 0.f, 0.f, 0.f};

  const unsigned short* kfh = g_kf + (size_t)h * NB_ * 4096;
  const unsigned short* vfh = g_vf + (size_t)h * NB_ * 4096;

  // fragment double-buffers (compile-time indexed after full unroll)
  bf16x8 ka0[2], ka1[2], vv01[2], vv23[2];

  // prologue: load KV block 0 fragments (coalesced bursts)
  {
    const int kb0 = lut_r[0];
    const unsigned short* kbp = kfh + ((size_t)kb0 * 4 + w) * 1024;
    ka0[0] = *(const bf16x8*)(kbp + lane * 8);
    ka1[0] = *(const bf16x8*)(kbp + 512 + lane * 8);
    const unsigned short* vbp = vfh + ((size_t)kb0 * 4 + w) * 1024 + lane * 16;
    vv01[0] = *(const bf16x8*)(vbp);
    vv23[0] = *(const bf16x8*)(vbp + 8);
  }

  #pragma unroll
  for (int j = 0; j < TK_; ++j) {
    const int cb = j & 1, nb = cb ^ 1;
    // issue next block's fragment loads (latency hides under compute)
    if (j + 1 < TK_) {
      const int kbn = lut_r[j + 1];
      const unsigned short* kbp = kfh + ((size_t)kbn * 4 + w) * 1024;
      ka0[nb] = *(const bf16x8*)(kbp + lane * 8);
      ka1[nb] = *(const bf16x8*)(kbp + 512 + lane * 8);
      const unsigned short* vbp = vfh + ((size_t)kbn * 4 + w) * 1024 + lane * 16;
      vv01[nb] = *(const bf16x8*)(vbp);
      vv23[nb] = *(const bf16x8*)(vbp + 8);
    }

    // ---- S = K Q^T : acc[g][r] = S[q=16g+l16][kv=16w+4quad+r] ------------
    f32x4 acc[4];
    __builtin_amdgcn_s_setprio(1);
    #pragma unroll
    for (int g = 0; g < 4; ++g) {
      f32x4 z = (f32x4){0.f, 0.f, 0.f, 0.f};
      z = __builtin_amdgcn_mfma_f32_16x16x32_bf16(ka0[cb], qb0[g], z, 0, 0, 0);
      z = __builtin_amdgcn_mfma_f32_16x16x32_bf16(ka1[cb], qb1[g], z, 0, 0, 0);
      acc[g] = z;
    }
    __builtin_amdgcn_s_setprio(0);

    // ---- no-max softmax (pre-scaled log2 units) + in-lane pack -----------
    bf16x4 pb[4];
    #pragma unroll
    for (int g = 0; g < 4; ++g) {
      const float p0 = exp2f(acc[g][0]), p1 = exp2f(acc[g][1]);
      const float p2 = exp2f(acc[g][2]), p3 = exp2f(acc[g][3]);
      lsum[g] += (p0 + p1) + (p2 + p3);
      unsigned int d0, d1;
      asm("v_cvt_pk_bf16_f32 %0, %1, %2" : "=v"(d0) : "v"(p0), "v"(p1));
      asm("v_cvt_pk_bf16_f32 %0, %1, %2" : "=v"(d1) : "v"(p2), "v"(p3));
      uint2 dd; dd.x = d0; dd.y = d1;
      pb[g] = __builtin_bit_cast(bf16x4, dd);
    }

    // ---- O^T += V^T P^T : 16x16x16, A and B straight from registers ------
    const bf16x4 va_[4] = { lo4(vv01[cb]), hi4(vv01[cb]),
                            lo4(vv23[cb]), hi4(vv23[cb]) };
    __builtin_amdgcn_s_setprio(1);
    #pragma unroll
    for (int n4 = 0; n4 < 4; ++n4)
      #pragma unroll
      for (int g = 0; g < 4; ++g)
        o[n4][g] = mfma16(va_[n4], pb[g], o[n4][g]);
    __builtin_amdgcn_s_setprio(0);
  }

  // ---- epilogue: cross-wave reduce (one-time) ----------------------------
  #pragma unroll
  for (int g = 0; g < 4; ++g) {
    float rs = lsum[g];
    rs += __shfl_xor(rs, 16, 64);
    rs += __shfl_xor(rs, 32, 64);
    lsum[g] = rs;                      // uniform across quads
  }
  if (quad == 0) {
    #pragma unroll
    for (int g = 0; g < 4; ++g) LDSr[w][16 * g + l16] = lsum[g];
  }
  __syncthreads();

  const int dr = t & 15, q0 = (t >> 4) * 4;
  float rinv[4];
  #pragma unroll
  for (int qq = 0; qq < 4; ++qq)
    rinv[qq] = 1.0f / (LDSr[0][q0 + qq] + LDSr[1][q0 + qq] +
                       LDSr[2][q0 + qq] + LDSr[3][q0 + qq]);

  const size_t obase = ((size_t)h * L_ + (size_t)m * 64) * D_;
  #pragma unroll
  for (int n4 = 0; n4 < 4; ++n4) {
    // publish this wave's O^T d-chunk
    #pragma unroll
    for (int g = 0; g < 4; ++g)
      #pragma unroll
      for (int r = 0; r < 4; ++r)
        LDSo[w][quad * 4 + r][16 * g + l16] = o[n4][g][r];
    __syncthreads();
    // sum 4 waves, normalize, store (coalesced 64B runs along d)
    #pragma unroll
    for (int qq = 0; qq < 4; ++qq) {
      const int qv = q0 + qq;
      const float s = LDSo[0][dr][qv] + LDSo[1][dr][qv] +
                      LDSo[2][dr][qv] + LDSo[3][dr][qv];
      out[obase + (size_t)qv * 64 + n4 * 16 + dr] = s * rinv[qq];
    }
    __syncthreads();
  }
}

extern "C" void kernel_launch(void* const* d_in, const int* in_sizes, int n_in,
                              void* d_out, int out_size, void* d_ws, size_t ws_size,
                              hipStream_t stream) {
  const float* q = (const float*)d_in[0];
  const float* k = (const float*)d_in[1];
  const float* v = (const float*)d_in[2];
  float* out = (float*)d_out;

  fusedpool_kernel<<<H_ * NB_, 256, 0, stream>>>(q, k, v);
  attn_kernel<<<H_ * MB_, 256, 0, stream>>>(out);
}